// Round 8
// baseline (766.148 us; speedup 1.0000x reference)
//
#include <hip/hip_runtime.h>

// MSDNet on gfx950 — round 19 RESUBMIT (previous bench aborted: MI355X
// container failed twice — infra, not kernel). Source identical to R19.
//
// R18 (380us) post-mortem: (512,4) caps VGPR at 128 but the A/B span
// buffers need 144-192 regs for D>=5 => 18/30 depths spilled to scratch,
// eating most of the 4-waves/SIMD win. This round:
//  - per-depth hybrid: D<=4 -> 4 px/lane @ 4 waves/SIMD (buffers 72 regs,
//    fits 128 cap); D>=5 -> R15's 8 px/lane @ 2 waves/SIMD (256 budget,
//    no spill).
//  - row-granular prefetch: refill each buffer row for pair p+2 right after
//    its last use in pair p's compute (named buffers, compile-time indices)
//    -> ~1.5-2x latency cover at zero extra registers.
// Accumulation order per px (pairs asc, rows 0-2, taps w0/w1/w2) unchanged
// => bit-identical numerics. Layout: feats = 15 channel-pairs (u32=2xf16) x
// 4 batches x 544x544; fdot2 contracts 2 ch/px/tap; depth 29 fuses 1x1 conv.

#define MSD_DEPTH 30
#define NB 4
#define IH 512
#define IW 512
#define HALO 16
#define WPp (IW + 2 * HALO)               /* 544 u32 per row */
#define HPp (IH + 2 * HALO)               /* 544 rows */
#define PLANE_U ((size_t)WPp * HPp)       /* u32 per subplane */
#define PSTR ((size_t)NB * PLANE_U)       /* pair stride (u32) */
#define NPAIR 15
#define NPIX (NB * IH * IW)
#define WPK_OFF ((size_t)20 << 20)        /* u32 offset: 80 MB into ws */
#define ZSTRIPS (32 * (WPp / 4) * NPAIR * NB)   /* top/bot: 261120 uint4 */
#define SSTRIPS (512 * 8 * NPAIR * NB)          /* sides:   245760 uint4 */
#define TOTZ (ZSTRIPS + SSTRIPS)

typedef _Float16 h2v __attribute__((ext_vector_type(2)));
typedef unsigned int u32;

__device__ __forceinline__ float fdot2u(u32 a, u32 b, float c) {
#if __has_builtin(__builtin_amdgcn_fdot2)
    return __builtin_amdgcn_fdot2(__builtin_bit_cast(h2v, a),
                                  __builtin_bit_cast(h2v, b), c, false);
#else
    h2v x = __builtin_bit_cast(h2v, a), y = __builtin_bit_cast(h2v, b);
    return c + (float)x[0] * (float)y[0] + (float)x[1] * (float)y[1];
#endif
}

// ---------------------------------------------------------------------------
// Preamble: pack weights + zero halos (rows AND side cols) + scale input.
// ---------------------------------------------------------------------------
__global__ __launch_bounds__(256) void preamble_kernel(const float* __restrict__ x,
                                                       const float* __restrict__ Wmsd,
                                                       const float* __restrict__ convW,
                                                       u32* __restrict__ feats,
                                                       u32* __restrict__ wpk,
                                                       u32* __restrict__ cpk,
                                                       const float* __restrict__ sw,
                                                       const float* __restrict__ sb) {
    int idx = blockIdx.x * 256 + threadIdx.x;

    if (idx < MSD_DEPTH * NPAIR * 9) {
        int I = idx / (NPAIR * 9);
        int rem = idx - I * (NPAIR * 9);
        int p = rem / 9, t = rem - p * 9;
        int NC = I + 1, c0 = 2 * p, c1 = 2 * p + 1;
        h2v pk;
        pk[0] = (_Float16)((c0 < NC) ? Wmsd[((size_t)I * MSD_DEPTH + c0) * 9 + t] : 0.f);
        pk[1] = (_Float16)((c1 < NC) ? Wmsd[((size_t)I * MSD_DEPTH + c1) * 9 + t] : 0.f);
        wpk[idx] = __builtin_bit_cast(u32, pk);
    }
    if (idx < NPAIR) {
        h2v pk;
        pk[0] = (_Float16)convW[2 * idx];
        pk[1] = (_Float16)convW[2 * idx + 1];
        cpk[idx] = __builtin_bit_cast(u32, pk);
    }

    if (idx < ZSTRIPS) {
        const int per = 32 * (WPp / 4); // 32 rows x 136 uint4 strips = 4352
        int sub = idx / per;
        int s = idx - sub * per;
        int rr = s / 136;
        int c4 = (s - rr * 136) * 4;
        int r = (rr < 16) ? rr : (IH + HALO) + (rr - 16);
        uint4 z = {0, 0, 0, 0};
        *(uint4*)(feats + (size_t)sub * PLANE_U + (size_t)r * WPp + c4) = z;
    } else if (idx < TOTZ) {
        int s = idx - ZSTRIPS;
        int sub = s >> 12;            // / 4096 (= 512 rows * 8 strips)
        int rem = s & 4095;
        int r = HALO + (rem >> 3);    // 16..527
        int e = rem & 7;
        int c4 = (e < 4) ? (e * 4) : (IW + HALO + (e - 4) * 4);
        uint4 z = {0, 0, 0, 0};
        *(uint4*)(feats + (size_t)sub * PLANE_U + (size_t)r * WPp + c4) = z;
    }

    if (idx < NPIX / 8) {
        int pix = idx * 8;
        int b = pix >> 18;
        int y = (pix >> 9) & 511;
        int xx = pix & 511;
        const float sws = sw[0], sbs = sb[0];
        u32 v[8];
#pragma unroll
        for (int j = 0; j < 8; ++j) {
            _Float16 h = (_Float16)(x[pix + j] * sws + sbs);
            v[j] = (u32)__builtin_bit_cast(unsigned short, h);
        }
        u32* q = feats + (size_t)b * PLANE_U + (size_t)(y + HALO) * WPp + HALO + xx;
        *(uint4*)q = *(uint4*)&v[0];
        *(uint4*)(q + 4) = *(uint4*)&v[4];
    }
}

// ---------------------------------------------------------------------------
// Variant A (D>=5): 8 px/lane, 2 waves/SIMD, 256-VGPR budget (R15 config).
// ---------------------------------------------------------------------------
template <int I>
__global__ __launch_bounds__(128, 2) void depth8_kernel(u32* __restrict__ feats,
                                                        const u32* __restrict__ wpk,
                                                        const u32* __restrict__ cpk,
                                                        const float* __restrict__ bias,
                                                        const float* __restrict__ convW,
                                                        const float* __restrict__ convB,
                                                        const float* __restrict__ soutw,
                                                        const float* __restrict__ soutb,
                                                        float* __restrict__ out) {
    constexpr int D = (I % 10) + 1;
    constexpr int NC = I + 1;
    constexpr int NP = (NC + 1) / 2;
    constexpr bool LAST = (I == MSD_DEPTH - 1);
    constexpr int C0 = (12 - D) >> 2;   // D<=8 -> 1, else 0
    constexpr int C1 = (19 + D) >> 2;   // D<=8 -> 6, else 7

    const int tid = threadIdx.x;
    const int widx = tid >> 6, lane = tid & 63;
    const int bid = blockIdx.x; // 1024 blocks x 2 waves = 2048 rows
    const int xcd = bid & 7;    // XCD band swizzle (validated R4-R8)
    const int kk = bid >> 3;
    const int b = xcd >> 1;
    const int y = (xcd & 1) * 256 + kk * 2 + widx;

    u32* const pb = feats + (size_t)b * PLANE_U + (size_t)(y + HALO) * WPp + HALO + lane * 8;

    float acc[8], ydot[8];
#pragma unroll
    for (int j = 0; j < 8; ++j) { acc[j] = 0.f; ydot[j] = 0.f; }

    const u32* const wrb = wpk + (size_t)I * (NPAIR * 9);

    u32 A[3][32], B[3][32];   // named double buffers (SROA-promoted)

    auto load_row = [&](u32* dst, int p, int r) {
        const u32* rp = pb + (size_t)p * PSTR + (ptrdiff_t)((r - 1) * (D * WPp));
#pragma unroll
        for (int c = C0; c <= C1; ++c)
            *(uint4*)&dst[4 * c] = *(const uint4*)(rp - 12 + 4 * c);
    };
    auto load_pair = [&](u32 (*bp)[32], int p) {
        load_row(bp[0], p, 0); load_row(bp[1], p, 1); load_row(bp[2], p, 2);
    };
    auto compute_r = [&](const u32* s, int p, int r) {
        const u32* wq = wrb + p * 9; // wave-uniform -> s_load
        const u32 w0 = wq[r * 3 + 0], w1 = wq[r * 3 + 1], w2 = wq[r * 3 + 2];
#pragma unroll
        for (int k = 0; k < 8; ++k) {
            float a = acc[k];
            a = fdot2u(s[12 - D + k], w0, a);
            a = fdot2u(s[12 + k],     w1, a);
            a = fdot2u(s[12 + D + k], w2, a);
            acc[k] = a;
        }
        if (LAST && r == 1) {
            const u32 cw = cpk[p];
#pragma unroll
            for (int k = 0; k < 8; ++k) ydot[k] = fdot2u(s[12 + k], cw, ydot[k]);
        }
    };

    // 2-deep pipeline with row-granular refill.
    load_pair(A, 0);
    if constexpr (NP >= 2) load_pair(B, 1);
    int p = 0;
    for (; p + 2 <= NP; p += 2) {
#pragma unroll
        for (int r = 0; r < 3; ++r) {
            compute_r(A[r], p, r);
            if (p + 2 < NP) load_row(A[r], p + 2, r);
        }
#pragma unroll
        for (int r = 0; r < 3; ++r) {
            compute_r(B[r], p + 1, r);
            if (p + 3 < NP) load_row(B[r], p + 3, r);
        }
    }
    if (p < NP) { compute_r(A[0], p, 0); compute_r(A[1], p, 1); compute_r(A[2], p, 2); }

    const float b0 = bias[I];
    if (!LAST) {
        u32 part[8];
        if constexpr ((NC & 1) != 0) {   // partner = center row of pair NP-1
            constexpr bool inA = (((NP - 1) & 1) == 0);
            const u32* s = inA ? A[1] : B[1];
#pragma unroll
            for (int j = 0; j < 8; ++j) part[j] = s[12 + j];
        }
        u32 mg[8];
#pragma unroll
        for (int j = 0; j < 8; ++j) {
            float h = acc[j] + b0;
            h = h > 0.f ? h : 0.f;
            u32 h16 = (u32)__builtin_bit_cast(unsigned short, (_Float16)h);
            if constexpr ((NC & 1) != 0)
                mg[j] = (part[j] & 0xFFFFu) | (h16 << 16);
            else
                mg[j] = h16;
        }
        u32* q = feats + (size_t)(NC >> 1) * PSTR + (size_t)b * PLANE_U +
                 (size_t)(y + HALO) * WPp + HALO + lane * 8;
        *(uint4*)q = *(uint4*)&mg[0];
        *(uint4*)(q + 4) = *(uint4*)&mg[4];
    } else {
        const float cw30 = convW[MSD_DEPTH];
        const float cb = convB[0], ow = soutw[0], ob = soutb[0];
        float* q = out + ((size_t)b * IH + y) * IW + lane * 8;
        float o[8];
#pragma unroll
        for (int j = 0; j < 8; ++j) {
            float h = acc[j] + b0;
            h = h > 0.f ? h : 0.f;
            float yv = ydot[j] + cw30 * h + cb;
            o[j] = yv * ow + ob;
        }
        *(uint4*)q = *(uint4*)&o[0];
        *(uint4*)(q + 4) = *(uint4*)&o[4];
    }
}

// ---------------------------------------------------------------------------
// Variant B (D<=4): 4 px/lane, 4 waves/SIMD (buffers 72 regs < 128 cap).
// ---------------------------------------------------------------------------
template <int I>
__global__ __launch_bounds__(512, 4) void depth4_kernel(u32* __restrict__ feats,
                                                        const u32* __restrict__ wpk,
                                                        const u32* __restrict__ cpk,
                                                        const float* __restrict__ bias,
                                                        const float* __restrict__ convW,
                                                        const float* __restrict__ convB,
                                                        const float* __restrict__ soutw,
                                                        const float* __restrict__ soutb,
                                                        float* __restrict__ out) {
    constexpr int D = (I % 10) + 1;
    constexpr int NC = I + 1;
    constexpr int NP = (NC + 1) / 2;
    constexpr bool LAST = (I == MSD_DEPTH - 1);
    constexpr int C0 = (12 - D) >> 2;   // D<=4 -> 2
    constexpr int C1 = (15 + D) >> 2;   // D<=4 -> 4

    const int tid = threadIdx.x;
    const int widx = tid >> 6, lane = tid & 63;
    const int bid = blockIdx.x;         // 512 blocks x 8 waves = 4096 half-rows
    const int xcd = bid & 7;
    const int kk = bid >> 3;
    const int b = xcd >> 1;
    const int y = (xcd & 1) * 256 + kk * 4 + (widx >> 1);
    const int h = widx & 1;
    const int xx = h * 256 + lane * 4;

    u32* const pb = feats + (size_t)b * PLANE_U + (size_t)(y + HALO) * WPp + HALO + xx;

    float acc[4], ydot[4];
#pragma unroll
    for (int j = 0; j < 4; ++j) { acc[j] = 0.f; ydot[j] = 0.f; }

    const u32* const wrb = wpk + (size_t)I * (NPAIR * 9);

    u32 A[3][20], B[3][20];

    auto load_row = [&](u32* dst, int p, int r) {
        const u32* rp = pb + (size_t)p * PSTR + (ptrdiff_t)((r - 1) * (D * WPp));
#pragma unroll
        for (int c = C0; c <= C1; ++c)
            *(uint4*)&dst[4 * c] = *(const uint4*)(rp - 12 + 4 * c);
    };
    auto load_pair = [&](u32 (*bp)[20], int p) {
        load_row(bp[0], p, 0); load_row(bp[1], p, 1); load_row(bp[2], p, 2);
    };
    auto compute_r = [&](const u32* s, int p, int r) {
        const u32* wq = wrb + p * 9;
        const u32 w0 = wq[r * 3 + 0], w1 = wq[r * 3 + 1], w2 = wq[r * 3 + 2];
#pragma unroll
        for (int k = 0; k < 4; ++k) {
            float a = acc[k];
            a = fdot2u(s[12 - D + k], w0, a);
            a = fdot2u(s[12 + k],     w1, a);
            a = fdot2u(s[12 + D + k], w2, a);
            acc[k] = a;
        }
        if (LAST && r == 1) {
            const u32 cw = cpk[p];
#pragma unroll
            for (int k = 0; k < 4; ++k) ydot[k] = fdot2u(s[12 + k], cw, ydot[k]);
        }
    };

    load_pair(A, 0);
    if constexpr (NP >= 2) load_pair(B, 1);
    int p = 0;
    for (; p + 2 <= NP; p += 2) {
#pragma unroll
        for (int r = 0; r < 3; ++r) {
            compute_r(A[r], p, r);
            if (p + 2 < NP) load_row(A[r], p + 2, r);
        }
#pragma unroll
        for (int r = 0; r < 3; ++r) {
            compute_r(B[r], p + 1, r);
            if (p + 3 < NP) load_row(B[r], p + 3, r);
        }
    }
    if (p < NP) { compute_r(A[0], p, 0); compute_r(A[1], p, 1); compute_r(A[2], p, 2); }

    const float b0 = bias[I];
    if (!LAST) {
        u32 part[4];
        if constexpr ((NC & 1) != 0) {
            constexpr bool inA = (((NP - 1) & 1) == 0);
            const u32* s = inA ? A[1] : B[1];
#pragma unroll
            for (int j = 0; j < 4; ++j) part[j] = s[12 + j];
        }
        u32 mg[4];
#pragma unroll
        for (int j = 0; j < 4; ++j) {
            float hh = acc[j] + b0;
            hh = hh > 0.f ? hh : 0.f;
            u32 h16 = (u32)__builtin_bit_cast(unsigned short, (_Float16)hh);
            if constexpr ((NC & 1) != 0)
                mg[j] = (part[j] & 0xFFFFu) | (h16 << 16);
            else
                mg[j] = h16;
        }
        u32* q = feats + (size_t)(NC >> 1) * PSTR + (size_t)b * PLANE_U +
                 (size_t)(y + HALO) * WPp + HALO + xx;
        *(uint4*)q = *(uint4*)&mg[0];
    } else {
        const float cw30 = convW[MSD_DEPTH];
        const float cb = convB[0], ow = soutw[0], ob = soutb[0];
        float* q = out + ((size_t)b * IH + y) * IW + xx;
        float o[4];
#pragma unroll
        for (int j = 0; j < 4; ++j) {
            float hh = acc[j] + b0;
            hh = hh > 0.f ? hh : 0.f;
            float yv = ydot[j] + cw30 * hh + cb;
            o[j] = yv * ow + ob;
        }
        *(uint4*)q = *(uint4*)&o[0];
    }
}

// ---------------------------------------------------------------------------
extern "C" void kernel_launch(void* const* d_in, const int* in_sizes, int n_in,
                              void* d_out, int out_size, void* d_ws, size_t ws_size,
                              hipStream_t stream) {
    const float* x     = (const float*)d_in[0];
    const float* Wmsd  = (const float*)d_in[1];
    const float* bias  = (const float*)d_in[2];
    const float* convW = (const float*)d_in[3];
    const float* convB = (const float*)d_in[4];
    const float* sinw  = (const float*)d_in[5];
    const float* sinb  = (const float*)d_in[6];
    const float* soutw = (const float*)d_in[7];
    const float* soutb = (const float*)d_in[8];
    float* out = (float*)d_out;

    u32* feats = (u32*)d_ws;                 // 15 pairs x 4 b x 544x544 u32 = 68 MB
    u32* wpk = feats + WPK_OFF;              // 80 MB offset
    u32* cpk = wpk + MSD_DEPTH * NPAIR * 9;

    preamble_kernel<<<(TOTZ + 255) / 256, 256, 0, stream>>>(x, Wmsd, convW,
                                                            feats, wpk, cpk,
                                                            sinw, sinb);

#define LNCH(I)                                                                     \
    do {                                                                            \
        if ((I % 10) + 1 <= 4)                                                      \
            depth4_kernel<I><<<512, 512, 0, stream>>>(feats, wpk, cpk, bias,        \
                                                      convW, convB, soutw, soutb,   \
                                                      out);                         \
        else                                                                        \
            depth8_kernel<I><<<1024, 128, 0, stream>>>(feats, wpk, cpk, bias,       \
                                                       convW, convB, soutw, soutb,  \
                                                       out);                        \
    } while (0);
    LNCH(0)  LNCH(1)  LNCH(2)  LNCH(3)  LNCH(4)
    LNCH(5)  LNCH(6)  LNCH(7)  LNCH(8)  LNCH(9)
    LNCH(10) LNCH(11) LNCH(12) LNCH(13) LNCH(14)
    LNCH(15) LNCH(16) LNCH(17) LNCH(18) LNCH(19)
    LNCH(20) LNCH(21) LNCH(22) LNCH(23) LNCH(24)
    LNCH(25) LNCH(26) LNCH(27) LNCH(28) LNCH(29)
#undef LNCH
}

// Round 9
// 403.196 us; speedup vs baseline: 1.9002x; 1.9002x over previous
//
#include <hip/hip_runtime.h>

// MSDNet on gfx950 — round 20. R19 post-mortem: row-granular prefetch
// interleave extended buffer live ranges; allocator landed at 128 VGPR and
// spilled (WRITE_SIZE 190MB/dispatch = scratch stores; depth8 72-90us).
// Same failure class as R14's indexed ring. Lesson: only the block-granular
// load_pair A/B loop promotes cleanly. This round = hybrid of the two best
// VERIFIED kernels, zero new machinery:
//  - D<=4 (12 depths): R18's 4 px/lane kernel verbatim (4 waves/SIMD,
//    buffers 72 regs < 128 cap, no spill — part of R18's 380us run).
//  - D>=5 (18 depths): R15's 8 px/lane kernel verbatim (2 waves/SIMD,
//    256-VGPR budget, no spill — part of R15's 390us run).
// Partner-from-regs merge (R17/R18-verified). Accumulation order unchanged
// => bit-identical numerics. Layout: feats = 15 channel-pairs (u32=2xf16) x
// 4 batches x 544x544; fdot2 contracts 2 ch/px/tap; depth 29 fuses 1x1 conv.

#define MSD_DEPTH 30
#define NB 4
#define IH 512
#define IW 512
#define HALO 16
#define WPp (IW + 2 * HALO)               /* 544 u32 per row */
#define HPp (IH + 2 * HALO)               /* 544 rows */
#define PLANE_U ((size_t)WPp * HPp)       /* u32 per subplane */
#define PSTR ((size_t)NB * PLANE_U)       /* pair stride (u32) */
#define NPAIR 15
#define NPIX (NB * IH * IW)
#define WPK_OFF ((size_t)20 << 20)        /* u32 offset: 80 MB into ws */
#define ZSTRIPS (32 * (WPp / 4) * NPAIR * NB)   /* top/bot: 261120 uint4 */
#define SSTRIPS (512 * 8 * NPAIR * NB)          /* sides:   245760 uint4 */
#define TOTZ (ZSTRIPS + SSTRIPS)

typedef _Float16 h2v __attribute__((ext_vector_type(2)));
typedef unsigned int u32;

__device__ __forceinline__ float fdot2u(u32 a, u32 b, float c) {
#if __has_builtin(__builtin_amdgcn_fdot2)
    return __builtin_amdgcn_fdot2(__builtin_bit_cast(h2v, a),
                                  __builtin_bit_cast(h2v, b), c, false);
#else
    h2v x = __builtin_bit_cast(h2v, a), y = __builtin_bit_cast(h2v, b);
    return c + (float)x[0] * (float)y[0] + (float)x[1] * (float)y[1];
#endif
}

// ---------------------------------------------------------------------------
// Preamble: pack weights + zero halos (rows AND side cols) + scale input.
// ---------------------------------------------------------------------------
__global__ __launch_bounds__(256) void preamble_kernel(const float* __restrict__ x,
                                                       const float* __restrict__ Wmsd,
                                                       const float* __restrict__ convW,
                                                       u32* __restrict__ feats,
                                                       u32* __restrict__ wpk,
                                                       u32* __restrict__ cpk,
                                                       const float* __restrict__ sw,
                                                       const float* __restrict__ sb) {
    int idx = blockIdx.x * 256 + threadIdx.x;

    if (idx < MSD_DEPTH * NPAIR * 9) {
        int I = idx / (NPAIR * 9);
        int rem = idx - I * (NPAIR * 9);
        int p = rem / 9, t = rem - p * 9;
        int NC = I + 1, c0 = 2 * p, c1 = 2 * p + 1;
        h2v pk;
        pk[0] = (_Float16)((c0 < NC) ? Wmsd[((size_t)I * MSD_DEPTH + c0) * 9 + t] : 0.f);
        pk[1] = (_Float16)((c1 < NC) ? Wmsd[((size_t)I * MSD_DEPTH + c1) * 9 + t] : 0.f);
        wpk[idx] = __builtin_bit_cast(u32, pk);
    }
    if (idx < NPAIR) {
        h2v pk;
        pk[0] = (_Float16)convW[2 * idx];
        pk[1] = (_Float16)convW[2 * idx + 1];
        cpk[idx] = __builtin_bit_cast(u32, pk);
    }

    if (idx < ZSTRIPS) {
        const int per = 32 * (WPp / 4); // 32 rows x 136 uint4 strips = 4352
        int sub = idx / per;
        int s = idx - sub * per;
        int rr = s / 136;
        int c4 = (s - rr * 136) * 4;
        int r = (rr < 16) ? rr : (IH + HALO) + (rr - 16);
        uint4 z = {0, 0, 0, 0};
        *(uint4*)(feats + (size_t)sub * PLANE_U + (size_t)r * WPp + c4) = z;
    } else if (idx < TOTZ) {
        int s = idx - ZSTRIPS;
        int sub = s >> 12;            // / 4096 (= 512 rows * 8 strips)
        int rem = s & 4095;
        int r = HALO + (rem >> 3);    // 16..527
        int e = rem & 7;
        int c4 = (e < 4) ? (e * 4) : (IW + HALO + (e - 4) * 4);
        uint4 z = {0, 0, 0, 0};
        *(uint4*)(feats + (size_t)sub * PLANE_U + (size_t)r * WPp + c4) = z;
    }

    if (idx < NPIX / 8) {
        int pix = idx * 8;
        int b = pix >> 18;
        int y = (pix >> 9) & 511;
        int xx = pix & 511;
        const float sws = sw[0], sbs = sb[0];
        u32 v[8];
#pragma unroll
        for (int j = 0; j < 8; ++j) {
            _Float16 h = (_Float16)(x[pix + j] * sws + sbs);
            v[j] = (u32)__builtin_bit_cast(unsigned short, h);
        }
        u32* q = feats + (size_t)b * PLANE_U + (size_t)(y + HALO) * WPp + HALO + xx;
        *(uint4*)q = *(uint4*)&v[0];
        *(uint4*)(q + 4) = *(uint4*)&v[4];
    }
}

// ---------------------------------------------------------------------------
// Variant A (D>=5): 8 px/lane, 2 waves/SIMD — R15 kernel verbatim
// (block-granular load_pair, named A/B double buffers).
// ---------------------------------------------------------------------------
template <int I>
__global__ __launch_bounds__(128, 2) void depth8_kernel(u32* __restrict__ feats,
                                                        const u32* __restrict__ wpk,
                                                        const u32* __restrict__ cpk,
                                                        const float* __restrict__ bias,
                                                        const float* __restrict__ convW,
                                                        const float* __restrict__ convB,
                                                        const float* __restrict__ soutw,
                                                        const float* __restrict__ soutb,
                                                        float* __restrict__ out) {
    constexpr int D = (I % 10) + 1;
    constexpr int NC = I + 1;
    constexpr int NP = (NC + 1) / 2;
    constexpr bool LAST = (I == MSD_DEPTH - 1);
    constexpr int C0 = (12 - D) >> 2;   // D<=8 -> 1, else 0
    constexpr int C1 = (19 + D) >> 2;   // D<=8 -> 6, else 7

    const int tid = threadIdx.x;
    const int widx = tid >> 6, lane = tid & 63;
    const int bid = blockIdx.x; // 1024 blocks x 2 waves = 2048 rows
    const int xcd = bid & 7;    // XCD band swizzle (validated R4-R8)
    const int kk = bid >> 3;
    const int b = xcd >> 1;
    const int y = (xcd & 1) * 256 + kk * 2 + widx;

    u32* const pb = feats + (size_t)b * PLANE_U + (size_t)(y + HALO) * WPp + HALO + lane * 8;

    float acc[8], ydot[8];
#pragma unroll
    for (int j = 0; j < 8; ++j) { acc[j] = 0.f; ydot[j] = 0.f; }

    const u32* const wrb = wpk + (size_t)I * (NPAIR * 9);

    u32 A[3][32], B[3][32];   // named double buffers (SROA-promoted)

    auto load_pair = [&](u32 (*bp)[32], int p) {
        const u32* pp = pb + (size_t)p * PSTR;
#pragma unroll
        for (int r = 0; r < 3; ++r) {
            const u32* rp = pp + (ptrdiff_t)(r - 1) * (D * WPp);
#pragma unroll
            for (int c = C0; c <= C1; ++c)
                *(uint4*)&bp[r][4 * c] = *(const uint4*)(rp - 12 + 4 * c);
        }
    };

    auto compute = [&](u32 (*bp)[32], int p) {
        const u32* wq = wrb + p * 9; // wave-uniform -> s_load
        const u32 cw = LAST ? cpk[p] : 0u;
#pragma unroll
        for (int r = 0; r < 3; ++r) {
            const u32* s = bp[r];
            const u32 w0 = wq[r * 3 + 0], w1 = wq[r * 3 + 1], w2 = wq[r * 3 + 2];
#pragma unroll
            for (int k = 0; k < 8; ++k) {
                float a = acc[k];
                a = fdot2u(s[12 - D + k], w0, a);   // const idx taps
                a = fdot2u(s[12 + k],     w1, a);
                a = fdot2u(s[12 + D + k], w2, a);
                acc[k] = a;
            }
            if (LAST && r == 1) {
#pragma unroll
                for (int k = 0; k < 8; ++k) ydot[k] = fdot2u(s[12 + k], cw, ydot[k]);
            }
        }
    };

    // 2-deep software pipeline over channel pairs (R12/R15-verified).
    load_pair(A, 0);
    int p = 0;
    for (; p + 2 <= NP; p += 2) {
        load_pair(B, p + 1);
        compute(A, p);
        if (p + 2 < NP) load_pair(A, p + 2);
        compute(B, p + 1);
    }
    if (p < NP) compute(A, p);

    const float b0 = bias[I];
    if (!LAST) {
        // Merge h (channel NC) into pair NC>>1. NC odd: hi16; partner lo16 =
        // channel NC-1 = center row of pair NP-1, still live in A or B regs.
        u32 part[8];
        if constexpr ((NC & 1) != 0) {
            constexpr bool inA = (((NP - 1) & 1) == 0);
            const u32* s = inA ? A[1] : B[1];
#pragma unroll
            for (int j = 0; j < 8; ++j) part[j] = s[12 + j];
        }
        u32 mg[8];
#pragma unroll
        for (int j = 0; j < 8; ++j) {
            float h = acc[j] + b0;
            h = h > 0.f ? h : 0.f;
            u32 h16 = (u32)__builtin_bit_cast(unsigned short, (_Float16)h);
            if constexpr ((NC & 1) != 0)
                mg[j] = (part[j] & 0xFFFFu) | (h16 << 16);
            else
                mg[j] = h16;
        }
        u32* q = feats + (size_t)(NC >> 1) * PSTR + (size_t)b * PLANE_U +
                 (size_t)(y + HALO) * WPp + HALO + lane * 8;
        *(uint4*)q = *(uint4*)&mg[0];
        *(uint4*)(q + 4) = *(uint4*)&mg[4];
    } else {
        const float cw30 = convW[MSD_DEPTH];
        const float cb = convB[0], ow = soutw[0], ob = soutb[0];
        float* q = out + ((size_t)b * IH + y) * IW + lane * 8;
        float o[8];
#pragma unroll
        for (int j = 0; j < 8; ++j) {
            float h = acc[j] + b0;
            h = h > 0.f ? h : 0.f;
            float yv = ydot[j] + cw30 * h + cb;
            o[j] = yv * ow + ob;
        }
        *(uint4*)q = *(uint4*)&o[0];
        *(uint4*)(q + 4) = *(uint4*)&o[4];
    }
}

// ---------------------------------------------------------------------------
// Variant B (D<=4): 4 px/lane, 4 waves/SIMD — R18 kernel verbatim
// (block-granular load_pair, buffers 72 regs < 128 cap).
// ---------------------------------------------------------------------------
template <int I>
__global__ __launch_bounds__(512, 4) void depth4_kernel(u32* __restrict__ feats,
                                                        const u32* __restrict__ wpk,
                                                        const u32* __restrict__ cpk,
                                                        const float* __restrict__ bias,
                                                        const float* __restrict__ convW,
                                                        const float* __restrict__ convB,
                                                        const float* __restrict__ soutw,
                                                        const float* __restrict__ soutb,
                                                        float* __restrict__ out) {
    constexpr int D = (I % 10) + 1;
    constexpr int NC = I + 1;
    constexpr int NP = (NC + 1) / 2;
    constexpr bool LAST = (I == MSD_DEPTH - 1);
    constexpr int C0 = (12 - D) >> 2;   // D<=4 -> 2
    constexpr int C1 = (15 + D) >> 2;   // D<=4 -> 4

    const int tid = threadIdx.x;
    const int widx = tid >> 6, lane = tid & 63;
    const int bid = blockIdx.x;         // 512 blocks x 8 waves = 4096 half-rows
    const int xcd = bid & 7;
    const int kk = bid >> 3;
    const int b = xcd >> 1;
    const int y = (xcd & 1) * 256 + kk * 4 + (widx >> 1);
    const int h = widx & 1;
    const int xx = h * 256 + lane * 4;

    u32* const pb = feats + (size_t)b * PLANE_U + (size_t)(y + HALO) * WPp + HALO + xx;

    float acc[4], ydot[4];
#pragma unroll
    for (int j = 0; j < 4; ++j) { acc[j] = 0.f; ydot[j] = 0.f; }

    const u32* const wrb = wpk + (size_t)I * (NPAIR * 9);

    u32 A[3][20], B[3][20];

    auto load_pair = [&](u32 (*bp)[20], int p) {
        const u32* pp = pb + (size_t)p * PSTR;
#pragma unroll
        for (int r = 0; r < 3; ++r) {
            const u32* rp = pp + (ptrdiff_t)(r - 1) * (D * WPp);
#pragma unroll
            for (int c = C0; c <= C1; ++c)
                *(uint4*)&bp[r][4 * c] = *(const uint4*)(rp - 12 + 4 * c);
        }
    };

    auto compute = [&](u32 (*bp)[20], int p) {
        const u32* wq = wrb + p * 9;
        const u32 cw = LAST ? cpk[p] : 0u;
#pragma unroll
        for (int r = 0; r < 3; ++r) {
            const u32* s = bp[r];
            const u32 w0 = wq[r * 3 + 0], w1 = wq[r * 3 + 1], w2 = wq[r * 3 + 2];
#pragma unroll
            for (int k = 0; k < 4; ++k) {
                float a = acc[k];
                a = fdot2u(s[12 - D + k], w0, a);
                a = fdot2u(s[12 + k],     w1, a);
                a = fdot2u(s[12 + D + k], w2, a);
                acc[k] = a;
            }
            if (LAST && r == 1) {
#pragma unroll
                for (int k = 0; k < 4; ++k) ydot[k] = fdot2u(s[12 + k], cw, ydot[k]);
            }
        }
    };

    load_pair(A, 0);
    int p = 0;
    for (; p + 2 <= NP; p += 2) {
        load_pair(B, p + 1);
        compute(A, p);
        if (p + 2 < NP) load_pair(A, p + 2);
        compute(B, p + 1);
    }
    if (p < NP) compute(A, p);

    const float b0 = bias[I];
    if (!LAST) {
        u32 part[4];
        if constexpr ((NC & 1) != 0) {
            constexpr bool inA = (((NP - 1) & 1) == 0);
            const u32* s = inA ? A[1] : B[1];
#pragma unroll
            for (int j = 0; j < 4; ++j) part[j] = s[12 + j];
        }
        u32 mg[4];
#pragma unroll
        for (int j = 0; j < 4; ++j) {
            float hh = acc[j] + b0;
            hh = hh > 0.f ? hh : 0.f;
            u32 h16 = (u32)__builtin_bit_cast(unsigned short, (_Float16)hh);
            if constexpr ((NC & 1) != 0)
                mg[j] = (part[j] & 0xFFFFu) | (h16 << 16);
            else
                mg[j] = h16;
        }
        u32* q = feats + (size_t)(NC >> 1) * PSTR + (size_t)b * PLANE_U +
                 (size_t)(y + HALO) * WPp + HALO + xx;
        *(uint4*)q = *(uint4*)&mg[0];
    } else {
        const float cw30 = convW[MSD_DEPTH];
        const float cb = convB[0], ow = soutw[0], ob = soutb[0];
        float* q = out + ((size_t)b * IH + y) * IW + xx;
        float o[4];
#pragma unroll
        for (int j = 0; j < 4; ++j) {
            float hh = acc[j] + b0;
            hh = hh > 0.f ? hh : 0.f;
            float yv = ydot[j] + cw30 * hh + cb;
            o[j] = yv * ow + ob;
        }
        *(uint4*)q = *(uint4*)&o[0];
    }
}

// ---------------------------------------------------------------------------
extern "C" void kernel_launch(void* const* d_in, const int* in_sizes, int n_in,
                              void* d_out, int out_size, void* d_ws, size_t ws_size,
                              hipStream_t stream) {
    const float* x     = (const float*)d_in[0];
    const float* Wmsd  = (const float*)d_in[1];
    const float* bias  = (const float*)d_in[2];
    const float* convW = (const float*)d_in[3];
    const float* convB = (const float*)d_in[4];
    const float* sinw  = (const float*)d_in[5];
    const float* sinb  = (const float*)d_in[6];
    const float* soutw = (const float*)d_in[7];
    const float* soutb = (const float*)d_in[8];
    float* out = (float*)d_out;

    u32* feats = (u32*)d_ws;                 // 15 pairs x 4 b x 544x544 u32 = 68 MB
    u32* wpk = feats + WPK_OFF;              // 80 MB offset
    u32* cpk = wpk + MSD_DEPTH * NPAIR * 9;

    preamble_kernel<<<(TOTZ + 255) / 256, 256, 0, stream>>>(x, Wmsd, convW,
                                                            feats, wpk, cpk,
                                                            sinw, sinb);

#define LNCH(I)                                                                     \
    do {                                                                            \
        if ((I % 10) + 1 <= 4)                                                      \
            depth4_kernel<I><<<512, 512, 0, stream>>>(feats, wpk, cpk, bias,        \
                                                      convW, convB, soutw, soutb,   \
                                                      out);                         \
        else                                                                        \
            depth8_kernel<I><<<1024, 128, 0, stream>>>(feats, wpk, cpk, bias,       \
                                                       convW, convB, soutw, soutb,  \
                                                       out);                        \
    } while (0);
    LNCH(0)  LNCH(1)  LNCH(2)  LNCH(3)  LNCH(4)
    LNCH(5)  LNCH(6)  LNCH(7)  LNCH(8)  LNCH(9)
    LNCH(10) LNCH(11) LNCH(12) LNCH(13) LNCH(14)
    LNCH(15) LNCH(16) LNCH(17) LNCH(18) LNCH(19)
    LNCH(20) LNCH(21) LNCH(22) LNCH(23) LNCH(24)
    LNCH(25) LNCH(26) LNCH(27) LNCH(28) LNCH(29)
#undef LNCH
}

// Round 10
// 382.524 us; speedup vs baseline: 2.0029x; 1.0540x over previous
//
#include <hip/hip_runtime.h>

// MSDNet on gfx950 — round 21. R20 post-mortem: hybrid (8px/2wave for D>=5)
// regressed vs R18's all-4px (403 vs 380.6) => spilled-but-4-waves beats
// clean-but-2-waves: TLP > spill-free codegen at these latency-bound
// occupancies. This round keeps all depths at 4 px/lane and removes the
// spills without giving up waves: per-depth VGPR cap via launch_bounds —
//  - D<=4:  (512,4) cap 128 (buffers 60 dw, fits; R18/R20-verified).
//  - D>=5:  (512,3) cap ~168 (3 waves/SIMD legal at <=168 VGPR; buffers
//           120 dw for D=5-8, 168 for D=9-10) — near-spill-free at 3 waves
//           vs R18's heavy spill at 4 waves and R20's no-spill at 2 waves.
// Block-granular A/B load_pair loop only (R14 ring / R19 row-interleave both
// demoted buffers to scratch). Accumulation order unchanged => bit-identical.
// Layout: feats = 15 channel-pairs (u32=2xf16) x 4 batches x 544x544;
// one wave = one 256-px half-row (4 px/lane); 512 blocks x 8 waves; XCD
// bands; fdot2 contracts 2 ch/px/tap; depth 29 fuses 1x1 conv + affine.

#define MSD_DEPTH 30
#define NB 4
#define IH 512
#define IW 512
#define HALO 16
#define WPp (IW + 2 * HALO)               /* 544 u32 per row */
#define HPp (IH + 2 * HALO)               /* 544 rows */
#define PLANE_U ((size_t)WPp * HPp)       /* u32 per subplane */
#define PSTR ((size_t)NB * PLANE_U)       /* pair stride (u32) */
#define NPAIR 15
#define NPIX (NB * IH * IW)
#define WPK_OFF ((size_t)20 << 20)        /* u32 offset: 80 MB into ws */
#define ZSTRIPS (32 * (WPp / 4) * NPAIR * NB)   /* top/bot: 261120 uint4 */
#define SSTRIPS (512 * 8 * NPAIR * NB)          /* sides:   245760 uint4 */
#define TOTZ (ZSTRIPS + SSTRIPS)

typedef _Float16 h2v __attribute__((ext_vector_type(2)));
typedef unsigned int u32;

__device__ __forceinline__ float fdot2u(u32 a, u32 b, float c) {
#if __has_builtin(__builtin_amdgcn_fdot2)
    return __builtin_amdgcn_fdot2(__builtin_bit_cast(h2v, a),
                                  __builtin_bit_cast(h2v, b), c, false);
#else
    h2v x = __builtin_bit_cast(h2v, a), y = __builtin_bit_cast(h2v, b);
    return c + (float)x[0] * (float)y[0] + (float)x[1] * (float)y[1];
#endif
}

// ---------------------------------------------------------------------------
// Preamble: pack weights + zero halos (rows AND side cols) + scale input.
// ---------------------------------------------------------------------------
__global__ __launch_bounds__(256) void preamble_kernel(const float* __restrict__ x,
                                                       const float* __restrict__ Wmsd,
                                                       const float* __restrict__ convW,
                                                       u32* __restrict__ feats,
                                                       u32* __restrict__ wpk,
                                                       u32* __restrict__ cpk,
                                                       const float* __restrict__ sw,
                                                       const float* __restrict__ sb) {
    int idx = blockIdx.x * 256 + threadIdx.x;

    if (idx < MSD_DEPTH * NPAIR * 9) {
        int I = idx / (NPAIR * 9);
        int rem = idx - I * (NPAIR * 9);
        int p = rem / 9, t = rem - p * 9;
        int NC = I + 1, c0 = 2 * p, c1 = 2 * p + 1;
        h2v pk;
        pk[0] = (_Float16)((c0 < NC) ? Wmsd[((size_t)I * MSD_DEPTH + c0) * 9 + t] : 0.f);
        pk[1] = (_Float16)((c1 < NC) ? Wmsd[((size_t)I * MSD_DEPTH + c1) * 9 + t] : 0.f);
        wpk[idx] = __builtin_bit_cast(u32, pk);
    }
    if (idx < NPAIR) {
        h2v pk;
        pk[0] = (_Float16)convW[2 * idx];
        pk[1] = (_Float16)convW[2 * idx + 1];
        cpk[idx] = __builtin_bit_cast(u32, pk);
    }

    if (idx < ZSTRIPS) {
        const int per = 32 * (WPp / 4); // 32 rows x 136 uint4 strips = 4352
        int sub = idx / per;
        int s = idx - sub * per;
        int rr = s / 136;
        int c4 = (s - rr * 136) * 4;
        int r = (rr < 16) ? rr : (IH + HALO) + (rr - 16);
        uint4 z = {0, 0, 0, 0};
        *(uint4*)(feats + (size_t)sub * PLANE_U + (size_t)r * WPp + c4) = z;
    } else if (idx < TOTZ) {
        int s = idx - ZSTRIPS;
        int sub = s >> 12;            // / 4096 (= 512 rows * 8 strips)
        int rem = s & 4095;
        int r = HALO + (rem >> 3);    // 16..527
        int e = rem & 7;
        int c4 = (e < 4) ? (e * 4) : (IW + HALO + (e - 4) * 4);
        uint4 z = {0, 0, 0, 0};
        *(uint4*)(feats + (size_t)sub * PLANE_U + (size_t)r * WPp + c4) = z;
    }

    if (idx < NPIX / 8) {
        int pix = idx * 8;
        int b = pix >> 18;
        int y = (pix >> 9) & 511;
        int xx = pix & 511;
        const float sws = sw[0], sbs = sb[0];
        u32 v[8];
#pragma unroll
        for (int j = 0; j < 8; ++j) {
            _Float16 h = (_Float16)(x[pix + j] * sws + sbs);
            v[j] = (u32)__builtin_bit_cast(unsigned short, h);
        }
        u32* q = feats + (size_t)b * PLANE_U + (size_t)(y + HALO) * WPp + HALO + xx;
        *(uint4*)q = *(uint4*)&v[0];
        *(uint4*)(q + 4) = *(uint4*)&v[4];
    }
}

// ---------------------------------------------------------------------------
// Depth kernel: 4 px/lane, per-depth wave cap (MINW), block-granular A/B.
// Taps: s[12-D+k], s[12+k], s[12+D+k], k<4; buffer chunks C0..C1 (SROA drops
// unwritten entries, so the [28] extent costs nothing for small D).
// ---------------------------------------------------------------------------
template <int I, int MINW>
__global__ __launch_bounds__(512, MINW) void depth_kernel(u32* __restrict__ feats,
                                                          const u32* __restrict__ wpk,
                                                          const u32* __restrict__ cpk,
                                                          const float* __restrict__ bias,
                                                          const float* __restrict__ convW,
                                                          const float* __restrict__ convB,
                                                          const float* __restrict__ soutw,
                                                          const float* __restrict__ soutb,
                                                          float* __restrict__ out) {
    constexpr int D = (I % 10) + 1;
    constexpr int NC = I + 1;
    constexpr int NP = (NC + 1) / 2;
    constexpr bool LAST = (I == MSD_DEPTH - 1);
    constexpr int C0 = (12 - D) >> 2;   // D<=4 -> 2, D<=8 -> 1, else 0
    constexpr int C1 = (15 + D) >> 2;   // D<=4 -> 4, D<=8 -> 5, else 6

    const int tid = threadIdx.x;
    const int widx = tid >> 6, lane = tid & 63;
    const int bid = blockIdx.x;         // 512 blocks x 8 waves = 4096 half-rows
    const int xcd = bid & 7;            // XCD band swizzle (validated R4-R8)
    const int kk = bid >> 3;
    const int b = xcd >> 1;
    const int y = (xcd & 1) * 256 + kk * 4 + (widx >> 1);
    const int h = widx & 1;
    const int xx = h * 256 + lane * 4;

    u32* const pb = feats + (size_t)b * PLANE_U + (size_t)(y + HALO) * WPp + HALO + xx;

    float acc[4], ydot[4];
#pragma unroll
    for (int j = 0; j < 4; ++j) { acc[j] = 0.f; ydot[j] = 0.f; }

    const u32* const wrb = wpk + (size_t)I * (NPAIR * 9);

    u32 A[3][28], B[3][28];   // named double buffers (SROA-promoted)

    auto load_pair = [&](u32 (*bp)[28], int p) {
        const u32* pp = pb + (size_t)p * PSTR;
#pragma unroll
        for (int r = 0; r < 3; ++r) {
            const u32* rp = pp + (ptrdiff_t)(r - 1) * (D * WPp);
#pragma unroll
            for (int c = C0; c <= C1; ++c)
                *(uint4*)&bp[r][4 * c] = *(const uint4*)(rp - 12 + 4 * c);
        }
    };

    auto compute = [&](u32 (*bp)[28], int p) {
        const u32* wq = wrb + p * 9;    // wave-uniform -> s_load
        const u32 cw = LAST ? cpk[p] : 0u;
#pragma unroll
        for (int r = 0; r < 3; ++r) {
            const u32* s = bp[r];
            const u32 w0 = wq[r * 3 + 0], w1 = wq[r * 3 + 1], w2 = wq[r * 3 + 2];
#pragma unroll
            for (int k = 0; k < 4; ++k) {
                float a = acc[k];
                a = fdot2u(s[12 - D + k], w0, a);   // const idx taps
                a = fdot2u(s[12 + k],     w1, a);
                a = fdot2u(s[12 + D + k], w2, a);
                acc[k] = a;
            }
            if (LAST && r == 1) {
#pragma unroll
                for (int k = 0; k < 4; ++k) ydot[k] = fdot2u(s[12 + k], cw, ydot[k]);
            }
        }
    };

    // 2-deep software pipeline over channel pairs (R12/R15-verified shape).
    load_pair(A, 0);
    int p = 0;
    for (; p + 2 <= NP; p += 2) {
        load_pair(B, p + 1);
        compute(A, p);
        if (p + 2 < NP) load_pair(A, p + 2);
        compute(B, p + 1);
    }
    if (p < NP) compute(A, p);

    const float b0 = bias[I];
    if (!LAST) {
        // Merge h (channel NC) into pair NC>>1. NC odd: hi16; partner lo16 =
        // channel NC-1 = center row of pair NP-1, still live in A or B regs.
        u32 part[4];
        if constexpr ((NC & 1) != 0) {
            constexpr bool inA = (((NP - 1) & 1) == 0);
            const u32* s = inA ? A[1] : B[1];
#pragma unroll
            for (int j = 0; j < 4; ++j) part[j] = s[12 + j];
        }
        u32 mg[4];
#pragma unroll
        for (int j = 0; j < 4; ++j) {
            float hh = acc[j] + b0;
            hh = hh > 0.f ? hh : 0.f;
            u32 h16 = (u32)__builtin_bit_cast(unsigned short, (_Float16)hh);
            if constexpr ((NC & 1) != 0)
                mg[j] = (part[j] & 0xFFFFu) | (h16 << 16);
            else
                mg[j] = h16;
        }
        u32* q = feats + (size_t)(NC >> 1) * PSTR + (size_t)b * PLANE_U +
                 (size_t)(y + HALO) * WPp + HALO + xx;
        *(uint4*)q = *(uint4*)&mg[0];
    } else {
        const float cw30 = convW[MSD_DEPTH];
        const float cb = convB[0], ow = soutw[0], ob = soutb[0];
        float* q = out + ((size_t)b * IH + y) * IW + xx;
        float o[4];
#pragma unroll
        for (int j = 0; j < 4; ++j) {
            float hh = acc[j] + b0;
            hh = hh > 0.f ? hh : 0.f;
            float yv = ydot[j] + cw30 * hh + cb;
            o[j] = yv * ow + ob;
        }
        *(uint4*)q = *(uint4*)&o[0];
    }
}

// ---------------------------------------------------------------------------
extern "C" void kernel_launch(void* const* d_in, const int* in_sizes, int n_in,
                              void* d_out, int out_size, void* d_ws, size_t ws_size,
                              hipStream_t stream) {
    const float* x     = (const float*)d_in[0];
    const float* Wmsd  = (const float*)d_in[1];
    const float* bias  = (const float*)d_in[2];
    const float* convW = (const float*)d_in[3];
    const float* convB = (const float*)d_in[4];
    const float* sinw  = (const float*)d_in[5];
    const float* sinb  = (const float*)d_in[6];
    const float* soutw = (const float*)d_in[7];
    const float* soutb = (const float*)d_in[8];
    float* out = (float*)d_out;

    u32* feats = (u32*)d_ws;                 // 15 pairs x 4 b x 544x544 u32 = 68 MB
    u32* wpk = feats + WPK_OFF;              // 80 MB offset
    u32* cpk = wpk + MSD_DEPTH * NPAIR * 9;

    preamble_kernel<<<(TOTZ + 255) / 256, 256, 0, stream>>>(x, Wmsd, convW,
                                                            feats, wpk, cpk,
                                                            sinw, sinb);

    // MINW: D<=4 -> 4 waves/SIMD (cap 128); D>=5 -> 3 waves/SIMD (cap ~168).
#define LNCH(I)                                                                     \
    depth_kernel<I, (((I % 10) + 1 <= 4) ? 4 : 3)><<<512, 512, 0, stream>>>(        \
        feats, wpk, cpk, bias, convW, convB, soutw, soutb, out);
    LNCH(0)  LNCH(1)  LNCH(2)  LNCH(3)  LNCH(4)
    LNCH(5)  LNCH(6)  LNCH(7)  LNCH(8)  LNCH(9)
    LNCH(10) LNCH(11) LNCH(12) LNCH(13) LNCH(14)
    LNCH(15) LNCH(16) LNCH(17) LNCH(18) LNCH(19)
    LNCH(20) LNCH(21) LNCH(22) LNCH(23) LNCH(24)
    LNCH(25) LNCH(26) LNCH(27) LNCH(28) LNCH(29)
#undef LNCH
}